// Round 3
// baseline (73.405 us; speedup 1.0000x reference)
//
#include <hip/hip_runtime.h>

constexpr int H = 192, W = 192, D = 192;

constexpr int BH = 8, BW = 8, BZ = 16;   // output tile per block (h, w, z)
constexpr int TY = 20, TX = 20;          // staged rows (y, x): tile + halo (+-6 .. +7)
constexpr int TZ = 32;                   // staged z slots: zg0 = z0-8 .. z0+23 (128B aligned)
constexpr int ZS = 33;                   // LDS row stride in dwords (+1 pad -> conflict-free)

__global__ __launch_bounds__(256) void st_tile(
    const float* __restrict__ I,
    const float* __restrict__ dxt,
    const float* __restrict__ dyt,
    const float* __restrict__ dzt,
    float* __restrict__ out)
{
    __shared__ float tile[TY * TX * ZS];   // 52,800 B -> 3 wg/CU

    const int tid = threadIdx.x;
    const int w0 = blockIdx.x * BW;
    const int h0 = blockIdx.y * BH;
    const int z0 = blockIdx.z * BZ;
    const int xg0 = w0 - 6, yg0 = h0 - 6, zg0 = z0 - 8;

    // voxel assignment: 4 consecutive z per thread
    const int zq = tid & 3, wl = (tid >> 2) & 7, hl = tid >> 5;
    const int h = h0 + hl, w = w0 + wl, z = z0 + zq * 4;
    const int t4 = (h * W + w) * (D / 4) + (z >> 2);

    // issue streaming loads early (independent of staging)
    float4 vx = reinterpret_cast<const float4*>(dxt)[t4];
    float4 vy = reinterpret_cast<const float4*>(dyt)[t4];
    float4 vz = reinterpret_cast<const float4*>(dzt)[t4];

    // ---- stage input neighborhood into LDS (coalesced, conflict-free) ----
    {
        const int zo = tid & 31;                       // z slot 0..31
        const int gz = min(max(zg0 + zo, 0), D - 1);   // volume-clamped source z
        int ry = 0, rx = tid >> 5;                     // row = ry*TX + rx, 8 rows/iter
        #pragma unroll 10
        for (int it = 0; it < 50; ++it) {              // 400 rows total
            int gy = min(max(yg0 + ry, 0), H - 1);
            int gx = min(max(xg0 + rx, 0), W - 1);
            tile[(ry * TX + rx) * ZS + zo] = I[(gy * W + gx) * D + gz];
            rx += 8; if (rx >= TX) { rx -= TX; ry += 1; }
        }
    }
    __syncthreads();

    float rxj[4] = {vx.x, vx.y, vx.z, vx.w};
    float ryj[4] = {vy.x, vy.y, vy.z, vy.w};
    float rzj[4] = {vz.x, vz.y, vz.z, vz.w};
    float ro[4];

    #pragma unroll
    for (int j = 0; j < 4; ++j) {
        float x = rxj[j] + (float)(w + 1);
        float y = ryj[j] + (float)(h + 1);
        float zz = rzj[j] + (float)(z + j + 1);

        int fx = (int)floorf(x);
        int fy = (int)floorf(y);
        int fz = (int)floorf(zz);

        // padded-coord clip [0, 193]
        int x0 = min(max(fx, 0), W + 1), x1 = min(max(fx + 1, 0), W + 1);
        int y0 = min(max(fy, 0), H + 1), y1 = min(max(fy + 1, 0), H + 1);
        int zp0 = min(max(fz, 0), D + 1), zp1 = min(max(fz + 1, 0), D + 1);

        float dx = (float)x1 - x;
        float dy = (float)y1 - y;
        float dz = (float)zp1 - zz;

        // unpadded indices
        int xi0 = x0 - 1, xi1 = x1 - 1;
        int yi0 = y0 - 1, yi1 = y1 - 1;
        int zi = zp0 - 1, zj = zp1 - 1;

        // fold OOB-zero into weights
        float ax0 = ((unsigned)xi0 < (unsigned)W) ? dx        : 0.0f;
        float ax1 = ((unsigned)xi1 < (unsigned)W) ? 1.0f - dx : 0.0f;
        float ay0 = ((unsigned)yi0 < (unsigned)H) ? dy        : 0.0f;
        float ay1 = ((unsigned)yi1 < (unsigned)H) ? 1.0f - dy : 0.0f;
        float az0 = ((unsigned)zi  < (unsigned)D) ? dz        : 0.0f;
        float az1 = ((unsigned)zj  < (unsigned)D) ? 1.0f - dz : 0.0f;

        // volume-clamped coords (match staged clamped slots)
        int xc0 = min(max(xi0, 0), W - 1), xc1 = min(max(xi1, 0), W - 1);
        int yc0 = min(max(yi0, 0), H - 1), yc1 = min(max(yi1, 0), H - 1);
        int zc  = min(max(zi, 0), D - 2);        // pair base: covers zc, zc+1

        bool zlo = (zi <= D - 2);   // z0-tap at pair.x else pair.y
        bool zhi = (zi >= 0);       // z1-tap at pair.y else pair.x

        // tile-local coords
        int lx0 = xc0 - xg0, lx1 = xc1 - xg0;
        int ly0 = yc0 - yg0, ly1 = yc1 - yg0;
        int lz  = zc - zg0;

        bool ok = ((unsigned)lx0 <= (unsigned)(TX - 1))
                & ((unsigned)lx1 <= (unsigned)(TX - 1))
                & ((unsigned)ly0 <= (unsigned)(TY - 1))
                & ((unsigned)ly1 <= (unsigned)(TY - 1))
                & ((unsigned)lz  <= (unsigned)(TZ - 2));

        float v000, v001, v010, v011, v100, v101, v110, v111;
        if (__builtin_expect(ok, 1)) {
            int b00 = (ly0 * TX + lx0) * ZS + lz;
            int b01 = (ly0 * TX + lx1) * ZS + lz;
            int b10 = (ly1 * TX + lx0) * ZS + lz;
            int b11 = (ly1 * TX + lx1) * ZS + lz;
            float a0 = tile[b00], a1 = tile[b00 + 1];
            float b0 = tile[b01], b1 = tile[b01 + 1];
            float c0 = tile[b10], c1 = tile[b10 + 1];
            float d0 = tile[b11], d1 = tile[b11 + 1];
            v000 = zlo ? a0 : a1;  v001 = zhi ? a1 : a0;
            v010 = zlo ? b0 : b1;  v011 = zhi ? b1 : b0;
            v100 = zlo ? c0 : c1;  v101 = zhi ? c1 : c0;
            v110 = zlo ? d0 : d1;  v111 = zhi ? d1 : d0;
        } else {
            // rare global fallback (|disp| beyond halo): exact same semantics
            int zc0 = min(max(zi, 0), D - 1), zc1 = min(max(zj, 0), D - 1);
            v000 = I[(yc0 * W + xc0) * D + zc0];
            v001 = I[(yc0 * W + xc0) * D + zc1];
            v010 = I[(yc0 * W + xc1) * D + zc0];
            v011 = I[(yc0 * W + xc1) * D + zc1];
            v100 = I[(yc1 * W + xc0) * D + zc0];
            v101 = I[(yc1 * W + xc0) * D + zc1];
            v110 = I[(yc1 * W + xc1) * D + zc0];
            v111 = I[(yc1 * W + xc1) * D + zc1];
        }

        float s00 = az0 * v000 + az1 * v001;   // (x0, y0)
        float s01 = az0 * v010 + az1 * v011;   // (x1, y0)
        float s10 = az0 * v100 + az1 * v101;   // (x0, y1)
        float s11 = az0 * v110 + az1 * v111;   // (x1, y1)

        ro[j] = ay0 * (ax0 * s00 + ax1 * s01)
              + ay1 * (ax0 * s10 + ax1 * s11);
    }

    reinterpret_cast<float4*>(out)[t4] = make_float4(ro[0], ro[1], ro[2], ro[3]);
}

extern "C" void kernel_launch(void* const* d_in, const int* in_sizes, int n_in,
                              void* d_out, int out_size, void* d_ws, size_t ws_size,
                              hipStream_t stream) {
    const float* I   = (const float*)d_in[0];
    const float* dxt = (const float*)d_in[1];
    const float* dyt = (const float*)d_in[2];
    const float* dzt = (const float*)d_in[3];
    float* out = (float*)d_out;

    dim3 grid(W / BW, H / BH, D / BZ);   // 24 x 24 x 12
    hipLaunchKernelGGL(st_tile, grid, dim3(256), 0, stream,
                       I, dxt, dyt, dzt, out);
}

// Round 4
// 53.852 us; speedup vs baseline: 1.3631x; 1.3631x over previous
//
#include <hip/hip_runtime.h>

constexpr int H = 192, W = 192, D = 192;
constexpr int BH = 8, BW = 8, BZ = 16;     // output tile per block
constexpr int TY = 16, TX = 16, TZ = 24;   // staged: x/y halo -4..+11, z -4..+19
constexpr int WD = W * D;
// LDS layout: [row = ly*TX + lx][z], stride TZ dwords (no pad).
// Chunk g (g = 0..1535) of 4 dwords lives at byte g*16 -> linear, b128-aligned.

// Exact reference semantics for one voxel, all-global (fallback path).
__device__ __forceinline__ float ref_voxel(const float* __restrict__ I,
                                           float x, float y, float zf)
{
    int fx = (int)floorf(x), fy = (int)floorf(y), fz = (int)floorf(zf);
    int x0 = min(max(fx, 0), W + 1), x1 = min(max(fx + 1, 0), W + 1);
    int y0 = min(max(fy, 0), H + 1), y1 = min(max(fy + 1, 0), H + 1);
    int zp0 = min(max(fz, 0), D + 1), zp1 = min(max(fz + 1, 0), D + 1);
    float dx = (float)x1 - x, dy = (float)y1 - y, dz = (float)zp1 - zf;
    int xi0 = x0 - 1, xi1 = x1 - 1, yi0 = y0 - 1, yi1 = y1 - 1;
    int zi = zp0 - 1, zj = zp1 - 1;
    float ax0 = ((unsigned)xi0 < (unsigned)W) ? dx       : 0.f;
    float ax1 = ((unsigned)xi1 < (unsigned)W) ? 1.f - dx : 0.f;
    float ay0 = ((unsigned)yi0 < (unsigned)H) ? dy       : 0.f;
    float ay1 = ((unsigned)yi1 < (unsigned)H) ? 1.f - dy : 0.f;
    float az0 = ((unsigned)zi  < (unsigned)D) ? dz       : 0.f;
    float az1 = ((unsigned)zj  < (unsigned)D) ? 1.f - dz : 0.f;
    int xc0 = min(max(xi0, 0), W - 1), xc1 = min(max(xi1, 0), W - 1);
    int yc0 = min(max(yi0, 0), H - 1), yc1 = min(max(yi1, 0), H - 1);
    int zc0 = min(max(zi, 0), D - 1),  zc1 = min(max(zj, 0), D - 1);
    const float* r00 = I + (yc0 * W + xc0) * D;
    const float* r01 = I + (yc0 * W + xc1) * D;
    const float* r10 = I + (yc1 * W + xc0) * D;
    const float* r11 = I + (yc1 * W + xc1) * D;
    float s00 = az0 * r00[zc0] + az1 * r00[zc1];
    float s01 = az0 * r01[zc0] + az1 * r01[zc1];
    float s10 = az0 * r10[zc0] + az1 * r10[zc1];
    float s11 = az0 * r11[zc0] + az1 * r11[zc1];
    return ay0 * (ax0 * s00 + ax1 * s01) + ay1 * (ax0 * s10 + ax1 * s11);
}

__global__ __launch_bounds__(256) void st_tile(
    const float* __restrict__ I,
    const float* __restrict__ dxt,
    const float* __restrict__ dyt,
    const float* __restrict__ dzt,
    float* __restrict__ out)
{
    __shared__ float tile[TY * TX * TZ];   // 24 KB -> 6 wg/CU by LDS

    const int tid = threadIdx.x;
    const int bx = blockIdx.x, by = blockIdx.y, bz = blockIdx.z;
    const int w0 = bx * BW, h0 = by * BH, z0 = bz * BZ;
    const int xg0 = w0 - 4, yg0 = h0 - 4, zg0 = z0 - 4;

    const int zq = tid & 3, wl = (tid >> 2) & 7, hl = tid >> 5;
    const int h = h0 + hl, w = w0 + wl, z = z0 + zq * 4;
    const int t4 = (h * W + w) * (D / 4) + (z >> 2);

    float4 vx = reinterpret_cast<const float4*>(dxt)[t4];
    float4 vy = reinterpret_cast<const float4*>(dyt)[t4];
    float4 vz = reinterpret_cast<const float4*>(dzt)[t4];

    const bool interior = (bx >= 1) & (bx <= 22) & (by >= 1) & (by <= 22)
                        & (bz >= 1) & (bz <= 10);

    float rxj[4] = {vx.x, vx.y, vx.z, vx.w};
    float ryj[4] = {vy.x, vy.y, vy.z, vy.w};
    float rzj[4] = {vz.x, vz.y, vz.z, vz.w};
    float ro[4];

    if (interior) {
        // ---------- fast staging: unclamped float4 loads ----------
        {
            const float* p0 = I + ((yg0 * W + xg0) * D + zg0);
            float4 vals[6];
            #pragma unroll
            for (int it = 0; it < 6; ++it) {
                int g = it * 256 + tid;          // chunk id
                int row = g / 6, c = g - row * 6;
                int ry = row >> 4, rx = row & 15;
                vals[it] = *reinterpret_cast<const float4*>(p0 + (ry * W + rx) * D + c * 4);
            }
            #pragma unroll
            for (int it = 0; it < 6; ++it) {
                *reinterpret_cast<float4*>(
                    reinterpret_cast<char*>(tile) + (size_t)(it * 4096 + tid * 16)) = vals[it];
            }
        }
        __syncthreads();

        // ---------- fast compute: no clamps, frac weights ----------
        #pragma unroll
        for (int j = 0; j < 4; ++j) {
            float ux = rxj[j] + (float)(wl + 4);          // tile-local x coord
            float uy = ryj[j] + (float)(hl + 4);
            float uz = rzj[j] + (float)(zq * 4 + j + 4);

            float fxf = floorf(ux), fyf = floorf(uy), fzf = floorf(uz);
            int lx0 = (int)fxf, ly0 = (int)fyf, lz0 = (int)fzf;
            float tx = ux - fxf, ty = uy - fyf, tz = uz - fzf;

            bool ok = ((unsigned)lx0 <= (unsigned)(TX - 2))
                    & ((unsigned)ly0 <= (unsigned)(TY - 2))
                    & ((unsigned)lz0 <= (unsigned)(TZ - 2));

            if (__builtin_expect(ok, 1)) {
                int base = (ly0 * TX + lx0) * TZ + lz0;
                float a0 = tile[base],        a1 = tile[base + 1];        // (y0,x0)
                float b0 = tile[base + TZ],   b1 = tile[base + TZ + 1];   // (y0,x1)
                float c0 = tile[base + TX*TZ],     c1 = tile[base + TX*TZ + 1];     // (y1,x0)
                float d0 = tile[base + TX*TZ+TZ],  d1 = tile[base + TX*TZ+TZ + 1];  // (y1,x1)
                float wz0 = 1.f - tz, wz1 = tz;
                float wx0 = 1.f - tx, wx1 = tx;
                float wy0 = 1.f - ty, wy1 = ty;
                float s00 = wz0 * a0 + wz1 * a1;
                float s01 = wz0 * b0 + wz1 * b1;
                float s10 = wz0 * c0 + wz1 * c1;
                float s11 = wz0 * d0 + wz1 * d1;
                ro[j] = wy0 * (wx0 * s00 + wx1 * s01) + wy1 * (wx0 * s10 + wx1 * s11);
            } else {
                // exact-reference global fallback (prob ~2e-4)
                float x = rxj[j] + (float)(w + 1);
                float y = ryj[j] + (float)(h + 1);
                float zf = rzj[j] + (float)(z + j + 1);
                ro[j] = ref_voxel(I, x, y, zf);
            }
        }
    } else {
        // ---------- border staging: per-element clamped, still chunked ----------
        {
            float4 vals[6];
            #pragma unroll
            for (int it = 0; it < 6; ++it) {
                int g = it * 256 + tid;
                int row = g / 6, c = g - row * 6;
                int ry = row >> 4, rx = row & 15;
                int gy = min(max(yg0 + ry, 0), H - 1);
                int gx = min(max(xg0 + rx, 0), W - 1);
                const float* rp = I + (gy * W + gx) * D;
                int zb = zg0 + c * 4;
                vals[it] = make_float4(rp[min(max(zb + 0, 0), D - 1)],
                                       rp[min(max(zb + 1, 0), D - 1)],
                                       rp[min(max(zb + 2, 0), D - 1)],
                                       rp[min(max(zb + 3, 0), D - 1)]);
            }
            #pragma unroll
            for (int it = 0; it < 6; ++it) {
                *reinterpret_cast<float4*>(
                    reinterpret_cast<char*>(tile) + (size_t)(it * 4096 + tid * 16)) = vals[it];
            }
        }
        __syncthreads();

        // ---------- border compute: full clamp + folded weights (R3-verified) ----------
        #pragma unroll
        for (int j = 0; j < 4; ++j) {
            float x = rxj[j] + (float)(w + 1);
            float y = ryj[j] + (float)(h + 1);
            float zf = rzj[j] + (float)(z + j + 1);

            int fx = (int)floorf(x), fy = (int)floorf(y), fz = (int)floorf(zf);
            int x0 = min(max(fx, 0), W + 1), x1 = min(max(fx + 1, 0), W + 1);
            int y0 = min(max(fy, 0), H + 1), y1 = min(max(fy + 1, 0), H + 1);
            int zp0 = min(max(fz, 0), D + 1), zp1 = min(max(fz + 1, 0), D + 1);

            float dx = (float)x1 - x, dy = (float)y1 - y, dz = (float)zp1 - zf;

            int xi0 = x0 - 1, xi1 = x1 - 1, yi0 = y0 - 1, yi1 = y1 - 1;
            int zi = zp0 - 1, zj2 = zp1 - 1;

            float ax0 = ((unsigned)xi0 < (unsigned)W) ? dx       : 0.f;
            float ax1 = ((unsigned)xi1 < (unsigned)W) ? 1.f - dx : 0.f;
            float ay0 = ((unsigned)yi0 < (unsigned)H) ? dy       : 0.f;
            float ay1 = ((unsigned)yi1 < (unsigned)H) ? 1.f - dy : 0.f;
            float az0 = ((unsigned)zi  < (unsigned)D) ? dz       : 0.f;
            float az1 = ((unsigned)zj2 < (unsigned)D) ? 1.f - dz : 0.f;

            int xc0 = min(max(xi0, 0), W - 1), xc1 = min(max(xi1, 0), W - 1);
            int yc0 = min(max(yi0, 0), H - 1), yc1 = min(max(yi1, 0), H - 1);
            int zc  = min(max(zi, 0), D - 2);

            bool zlo = (zi <= D - 2);
            bool zhi = (zi >= 0);

            int lx0 = xc0 - xg0, lx1 = xc1 - xg0;
            int ly0 = yc0 - yg0, ly1 = yc1 - yg0;
            int lz  = zc - zg0;

            bool ok = ((unsigned)lx0 <= (unsigned)(TX - 1))
                    & ((unsigned)lx1 <= (unsigned)(TX - 1))
                    & ((unsigned)ly0 <= (unsigned)(TY - 1))
                    & ((unsigned)ly1 <= (unsigned)(TY - 1))
                    & ((unsigned)lz  <= (unsigned)(TZ - 2));

            if (__builtin_expect(ok, 1)) {
                int b00 = (ly0 * TX + lx0) * TZ + lz;
                int b01 = (ly0 * TX + lx1) * TZ + lz;
                int b10 = (ly1 * TX + lx0) * TZ + lz;
                int b11 = (ly1 * TX + lx1) * TZ + lz;
                float a0 = tile[b00], a1 = tile[b00 + 1];
                float b0 = tile[b01], b1 = tile[b01 + 1];
                float c0 = tile[b10], c1 = tile[b10 + 1];
                float d0 = tile[b11], d1 = tile[b11 + 1];
                float v000 = zlo ? a0 : a1, v001 = zhi ? a1 : a0;
                float v010 = zlo ? b0 : b1, v011 = zhi ? b1 : b0;
                float v100 = zlo ? c0 : c1, v101 = zhi ? c1 : c0;
                float v110 = zlo ? d0 : d1, v111 = zhi ? d1 : d0;
                float s00 = az0 * v000 + az1 * v001;
                float s01 = az0 * v010 + az1 * v011;
                float s10 = az0 * v100 + az1 * v101;
                float s11 = az0 * v110 + az1 * v111;
                ro[j] = ay0 * (ax0 * s00 + ax1 * s01)
                      + ay1 * (ax0 * s10 + ax1 * s11);
            } else {
                ro[j] = ref_voxel(I, x, y, zf);
            }
        }
    }

    reinterpret_cast<float4*>(out)[t4] = make_float4(ro[0], ro[1], ro[2], ro[3]);
}

extern "C" void kernel_launch(void* const* d_in, const int* in_sizes, int n_in,
                              void* d_out, int out_size, void* d_ws, size_t ws_size,
                              hipStream_t stream) {
    const float* I   = (const float*)d_in[0];
    const float* dxt = (const float*)d_in[1];
    const float* dyt = (const float*)d_in[2];
    const float* dzt = (const float*)d_in[3];
    float* out = (float*)d_out;

    dim3 grid(W / BW, H / BH, D / BZ);   // 24 x 24 x 12
    hipLaunchKernelGGL(st_tile, grid, dim3(256), 0, stream,
                       I, dxt, dyt, dzt, out);
}